// Round 10
// baseline (282.163 us; speedup 1.0000x reference)
//
#include <hip/hip_runtime.h>

typedef unsigned short ushort_t;
typedef __bf16 bf16x8 __attribute__((ext_vector_type(8)));
typedef unsigned short ushort8_t __attribute__((ext_vector_type(8)));
typedef unsigned short ushort4_t __attribute__((ext_vector_type(4)));
typedef float floatx4 __attribute__((ext_vector_type(4)));
typedef unsigned int uint4_t __attribute__((ext_vector_type(4)));
typedef unsigned int uint2_t __attribute__((ext_vector_type(2)));

__device__ __forceinline__ ushort_t f2bf(float f) {
    unsigned int u = __float_as_uint(f);
    u += 0x7FFFu + ((u >> 16) & 1u);  // RNE
    return (ushort_t)(u >> 16);
}
__device__ __forceinline__ float bf2f(ushort_t b) {
    return __uint_as_float(((unsigned int)b) << 16);
}
__device__ __forceinline__ bf16x8 ld_frag(const ushort_t* p) {
    ushort8_t u = *(const ushort8_t*)p;
    return __builtin_bit_cast(bf16x8, u);
}
__device__ __forceinline__ unsigned pack_trunc(float lo, float hi) {
    return __builtin_amdgcn_perm(__float_as_uint(hi), __float_as_uint(lo), 0x07060302u);
}
__device__ __forceinline__ floatx4 mfma16(bf16x8 a, bf16x8 b, floatx4 c) {
    return __builtin_amdgcn_mfma_f32_16x16x32_bf16(a, b, c, 0, 0, 0);
}
// dst.high32lanes <-> src.low32lanes (both regs updated)
__device__ __forceinline__ void pl32swap(unsigned& a, unsigned& b) {
    asm volatile("v_permlane32_swap_b32 %0, %1" : "+v"(a), "+v"(b));
}
// dst odd 16-rows <-> src even 16-rows (both regs updated)
__device__ __forceinline__ void pl16swap(unsigned& a, unsigned& b) {
    asm volatile("v_permlane16_swap_b32 %0, %1" : "+v"(a), "+v"(b));
}
// 8x f32 -> 8x bf16 (HW RNE, compiler fuses into v_cvt_pk_bf16_f32 pairs;
// identical rounding to f2bf so numerics match the old cvt_dual pass)
__device__ __forceinline__ ushort8_t cvt8(float4 a, float4 b) {
    bf16x8 w;
    w[0] = (__bf16)a.x; w[1] = (__bf16)a.y; w[2] = (__bf16)a.z; w[3] = (__bf16)a.w;
    w[4] = (__bf16)b.x; w[5] = (__bf16)b.y; w[6] = (__bf16)b.z; w[7] = (__bf16)b.w;
    return __builtin_bit_cast(ushort8_t, w);
}

// ---------------- GEMM: C[M,N] = A[M,K]*B[N,K]^T, K=1024 compile-time ----------------
// Round 10: cvt kernels ELIMINATED -- fp32 operands are converted during LDS
// staging (reg-stage: global_load_dwordx4 x2 -> cvt -> swizzled ds_write_b128).
//   MODE 2 (QKV):   A = x (fp32), B = qkv_w (fp32)
//   MODE 0 (proj):  A = y (bf16), B = c_proj_w (fp32)
// Geometry = round 8's proven 256x128 / 8 waves (4Mx2N, per-wave 64x64) / BK=64.
// 2 LDS buffers (96KB, 1 block/CU): gemm1 grid 768 = 3 exact rounds, gemm2
// grid 256 = 1 exact round (no idle tails).  T2 swizzle now applied on the
// WRITE side directly (no gload_lds constraint): write col (cc*8)^((row&7)*8),
// read col (ks*32+quad*8)^((l16&7)*8) -- same involution as rounds 6-9
// (bank conflicts measured 0).  Schedule per tile (T14 split):
//   LOAD(t+1)->regs  |  ds_read frags(t)  |  MFMA x32 (setprio)  |
//   cvt+WRITE(t+1) to other buffer  |  fused "lgkmcnt(0); s_barrier"
// No vmcnt drain at barriers: register loads are wave-private; only the
// ds_writes need visibility (lgkmcnt) before the barrier.  Race audit:
// WRITE targets buf (t+1)&1, whose last reader finished behind the t-1
// barrier; no wave can lag >1 tile (each tile ends in a full barrier).
template <int MODE>
__global__ __launch_bounds__(512, 2) void gemm_f(const ushort_t* __restrict__ Abf,
                                                 const float* __restrict__ Af,
                                                 const float* __restrict__ Bf,
                                                 const float* __restrict__ bias,
                                                 void* __restrict__ Cout,
                                                 ushort_t* __restrict__ vt, int N) {
    constexpr bool AF32 = (MODE == 2);
    constexpr int K = 1024;
    __shared__ __attribute__((aligned(16))) ushort_t As[2][256 * 64];  // 2 x 32KB
    __shared__ __attribute__((aligned(16))) ushort_t Bs[2][128 * 64];  // 2 x 16KB
    const int tid = threadIdx.x;
    const int lane = tid & 63, w = tid >> 6;
    const int quad = lane >> 4, l16 = lane & 15;
    const int wm = w >> 1, wn = w & 1;  // 4M x 2N wave grid, per-wave 64x64
    const int m0 = blockIdx.y * 256, n0 = blockIdx.x * 128;

    // staging coords: 512 threads; chunk = 64 rows x 64 cols bf16 (8KB);
    // thread covers row r512, col-chunk cc (8 elems = 16B)
    const int r512 = tid >> 3, cc = tid & 7;
    const int wsw = (r512 & 7) * 8;  // write-side XOR (T2)
    const int rsw = (l16 & 7) * 8;   // read-side XOR

    const float* pAf[4];
    const ushort_t* pAb[4];
    const float* pBf[2];
#pragma unroll
    for (int c = 0; c < 4; ++c) {
        if constexpr (AF32)
            pAf[c] = Af + (size_t)(m0 + c * 64 + r512) * K + cc * 8;
        else
            pAb[c] = Abf + (size_t)(m0 + c * 64 + r512) * K + cc * 8;
    }
#pragma unroll
    for (int c = 0; c < 2; ++c)
        pBf[c] = Bf + (size_t)(n0 + c * 64 + r512) * K + cc * 8;

    float4 raf[4][2];
    ushort8_t rab[4];
    float4 rbf[2][2];

    auto LOAD = [&](int kt) {
        const int ko = kt * 64;
#pragma unroll
        for (int c = 0; c < 4; ++c) {
            if constexpr (AF32) {
                raf[c][0] = *(const float4*)(pAf[c] + ko);
                raf[c][1] = *(const float4*)(pAf[c] + ko + 4);
            } else {
                rab[c] = *(const ushort8_t*)(pAb[c] + ko);
            }
        }
#pragma unroll
        for (int c = 0; c < 2; ++c) {
            rbf[c][0] = *(const float4*)(pBf[c] + ko);
            rbf[c][1] = *(const float4*)(pBf[c] + ko + 4);
        }
    };
    auto WRITE = [&](int buf) {
#pragma unroll
        for (int c = 0; c < 4; ++c) {
            ushort8_t v;
            if constexpr (AF32)
                v = cvt8(raf[c][0], raf[c][1]);
            else
                v = rab[c];
            *(ushort8_t*)&As[buf][(c * 64 + r512) * 64 + ((cc * 8) ^ wsw)] = v;
        }
#pragma unroll
        for (int c = 0; c < 2; ++c)
            *(ushort8_t*)&Bs[buf][(c * 64 + r512) * 64 + ((cc * 8) ^ wsw)] =
                cvt8(rbf[c][0], rbf[c][1]);
    };

    floatx4 acc[4][4] = {};

    // prologue: tile 0 staged to buf0
    LOAD(0);
    WRITE(0);
    asm volatile("s_waitcnt lgkmcnt(0)\ns_barrier" ::: "memory");

#pragma unroll
    for (int t = 0; t < 16; ++t) {
        if (t < 15) LOAD(t + 1);  // issue early: latency hides under reads+MFMA
        const int cb = t & 1;

        bf16x8 af[4][2], bfr[4][2];
#pragma unroll
        for (int mt = 0; mt < 4; ++mt)
#pragma unroll
            for (int ks = 0; ks < 2; ++ks)
                af[mt][ks] = ld_frag(&As[cb][(wm * 64 + mt * 16 + l16) * 64 +
                                             ((ks * 32 + quad * 8) ^ rsw)]);
#pragma unroll
        for (int nt = 0; nt < 4; ++nt)
#pragma unroll
            for (int ks = 0; ks < 2; ++ks)
                bfr[nt][ks] = ld_frag(&Bs[cb][(wn * 64 + nt * 16 + l16) * 64 +
                                              ((ks * 32 + quad * 8) ^ rsw)]);
        __builtin_amdgcn_s_setprio(1);
#pragma unroll
        for (int mt = 0; mt < 4; ++mt)
#pragma unroll
            for (int nt = 0; nt < 4; ++nt) {
                acc[mt][nt] = mfma16(af[mt][0], bfr[nt][0], acc[mt][nt]);
                acc[mt][nt] = mfma16(af[mt][1], bfr[nt][1], acc[mt][nt]);
            }
        __builtin_amdgcn_s_setprio(0);

        if (t < 15) WRITE(cb ^ 1);
        asm volatile("s_waitcnt lgkmcnt(0)\ns_barrier" ::: "memory");
    }

    if constexpr (MODE == 2) {
        // fused RoPE on q/k heads (wave spans exactly one 64-wide head)
        if (n0 + wn * 64 < 2048) {
            float afreq = exp2f((float)l16 * (-10.0f / 15.0f));
#pragma unroll
            for (int mt = 0; mt < 4; ++mt) {
                int rowb = m0 + wm * 64 + mt * 16 + quad * 4;
#pragma unroll
                for (int r = 0; r < 4; ++r) {
                    int t = (rowb + r) & 2047;
                    float th = (float)t * afreq;
                    float sn, cs;
                    __sincosf(th, &sn, &cs);
                    float q1 = acc[mt][0][r], q2 = acc[mt][2][r];
                    acc[mt][0][r] = q1 * cs + q2 * sn;
                    acc[mt][2][r] = -q1 * sn + q2 * cs;
                }
            }
        }
    }

#pragma unroll
    for (int mt = 0; mt < 4; ++mt) {
        int row = m0 + wm * 64 + mt * 16 + quad * 4;
#pragma unroll
        for (int nt = 0; nt < 4; ++nt) {
            int nglob = n0 + wn * 64 + nt * 16 + l16;
            if constexpr (MODE == 0) {
                float bv = bias ? bias[nglob] : 0.0f;
#pragma unroll
                for (int r = 0; r < 4; ++r)
                    ((float*)Cout)[(size_t)(row + r) * N + nglob] = acc[mt][nt][r] + bv;
            } else {
                if (nglob < 2048) {
#pragma unroll
                    for (int r = 0; r < 4; ++r)
                        ((ushort_t*)Cout)[(size_t)(row + r) * 2048 + nglob] =
                            f2bf(acc[mt][nt][r]);
                } else {
                    int d = nglob & 63, hh = (nglob >> 6) & 15;
                    int bb = row >> 11, t = row & 2047;
                    ushort4_t pk;
                    pk.x = f2bf(acc[mt][nt][0]);
                    pk.y = f2bf(acc[mt][nt][1]);
                    pk.z = f2bf(acc[mt][nt][2]);
                    pk.w = f2bf(acc[mt][nt][3]);
                    *(ushort4_t*)&vt[(((size_t)bb * 16 + hh) * 64 + d) * 2048 + t] = pk;
                }
            }
        }
    }
}

// ---------------- Flash attention (unchanged from round 7) ----------------
#define ATT_SCALE 0.18033688011112042f /* 0.125 * log2(e) */

template <bool DIAG>
__device__ __forceinline__ void attn_step(
    const ushort_t* __restrict__ Ks, const ushort_t* __restrict__ Vt,
    const bf16x8 (&qf)[2][2], floatx4 (&o)[2][4], floatx4 (&lac)[2], float (&m_)[2],
    int quad, int l16, int sw8, int mhi, int qrel) {
    ushort8_t ou;
#pragma unroll
    for (int j = 0; j < 8; ++j) ou[j] = 0x3F80;
    const bf16x8 vONE = __builtin_bit_cast(bf16x8, ou);

    // ---- QK^T from LDS-staged K ----
    floatx4 s[8][2];
    __builtin_amdgcn_s_setprio(1);
#pragma unroll
    for (int mt = 0; mt < 8; ++mt) {
        if (DIAG && mt > mhi) continue;
        const ushort_t* kr = &Ks[(mt * 16 + l16) * 64];
        bf16x8 k0 = ld_frag(kr + ((quad * 8) ^ sw8));
        bf16x8 k1 = ld_frag(kr + ((32 + quad * 8) ^ sw8));
#pragma unroll
        for (int nt = 0; nt < 2; ++nt) {
            floatx4 z = {};
            z = mfma16(k0, qf[nt][0], z);
            s[mt][nt] = mfma16(k1, qf[nt][1], z);
        }
    }
    __builtin_amdgcn_s_setprio(0);

    if (DIAG) {
#pragma unroll
        for (int mt = 0; mt < 8; ++mt) {
            if (mt > mhi) continue;
#pragma unroll
            for (int nt = 0; nt < 2; ++nt)
#pragma unroll
                for (int r = 0; r < 4; ++r)
                    if (mt * 16 + quad * 4 + r > qrel + nt * 16 + l16)
                        s[mt][nt][r] = -3e38f;
        }
    }

    // ---- online softmax with defer-max (T13) ----
    float mx[2];
#pragma unroll
    for (int nt = 0; nt < 2; ++nt) {
        float m0 = -3e38f;
#pragma unroll
        for (int mt = 0; mt < 8; ++mt) {
            if (DIAG && mt > mhi) continue;
            m0 = fmaxf(m0, fmaxf(fmaxf(s[mt][nt][0], s[mt][nt][1]),
                                 fmaxf(s[mt][nt][2], s[mt][nt][3])));
        }
        m0 = fmaxf(m0, __shfl_xor(m0, 16));
        m0 = fmaxf(m0, __shfl_xor(m0, 32));
        mx[nt] = m0;
    }
    bool resc = !__all((mx[0] - m_[0] <= 8.0f) && (mx[1] - m_[1] <= 8.0f));
    if (resc) {
        float alpha_l[2];
#pragma unroll
        for (int nt = 0; nt < 2; ++nt) {
            float mnew = fmaxf(m_[nt], mx[nt]);
            alpha_l[nt] = __builtin_amdgcn_exp2f(m_[nt] - mnew);
            m_[nt] = mnew;
        }
#pragma unroll
        for (int mtq = 0; mtq < 2; ++mtq)
#pragma unroll
            for (int r = 0; r < 4; ++r) {
                float ao = __shfl(alpha_l[mtq], quad * 4 + r);
                lac[mtq][r] *= ao;
#pragma unroll
                for (int ntd = 0; ntd < 4; ++ntd) o[mtq][ntd][r] *= ao;
            }
    }
#pragma unroll
    for (int nt = 0; nt < 2; ++nt)
#pragma unroll
        for (int mt = 0; mt < 8; ++mt) {
            if (DIAG && mt > mhi) continue;
#pragma unroll
            for (int r = 0; r < 4; ++r)
                s[mt][nt][r] = __builtin_amdgcn_exp2f(s[mt][nt][r] - m_[nt]);
        }

    // ---- in-register P transpose (verified round 2) ----
    uint2_t pk[2][8];
#pragma unroll
    for (int nt = 0; nt < 2; ++nt)
#pragma unroll
        for (int mt = 0; mt < 8; ++mt) {
            if (DIAG && mt > mhi) continue;
            pk[nt][mt].x = pack_trunc(s[mt][nt][0], s[mt][nt][1]);
            pk[nt][mt].y = pack_trunc(s[mt][nt][2], s[mt][nt][3]);
        }

    __builtin_amdgcn_s_setprio(1);
#pragma unroll
    for (int kc = 0; kc < 4; ++kc) {
        if (DIAG && kc > (mhi >> 1)) continue;
        bf16x8 ap[2];
#pragma unroll
        for (int nt = 0; nt < 2; ++nt) {
            unsigned a0 = pk[nt][2 * kc].x, a1 = pk[nt][2 * kc].y;
            unsigned b0 = pk[nt][2 * kc + 1].x, b1 = pk[nt][2 * kc + 1].y;
            pl32swap(a0, b0);
            pl16swap(a0, b0);
            pl32swap(a1, b1);
            pl16swap(a1, b1);
            uint4_t ud;
            ud[0] = a0; ud[1] = a1; ud[2] = b0; ud[3] = b1;
            ap[nt] = __builtin_bit_cast(bf16x8, ud);
        }
        lac[0] = mfma16(ap[0], vONE, lac[0]);
        lac[1] = mfma16(ap[1], vONE, lac[1]);
#pragma unroll
        for (int ntd = 0; ntd < 4; ++ntd) {
            bf16x8 bv = ld_frag(&Vt[(ntd * 16 + l16) * 136 + kc * 32 + quad * 8]);
            o[0][ntd] = mfma16(ap[0], bv, o[0][ntd]);
            o[1][ntd] = mfma16(ap[1], bv, o[1][ntd]);
        }
    }
    __builtin_amdgcn_s_setprio(0);
}

__global__ __launch_bounds__(256, 2) void attn_kernel(const ushort_t* __restrict__ qk,
                                                      const ushort_t* __restrict__ vt,
                                                      ushort_t* __restrict__ y) {
    __shared__ __attribute__((aligned(16))) ushort_t Ks[128 * 64];   // 16 KB
    __shared__ __attribute__((aligned(16))) ushort_t Vt[64 * 136];   // 17 KB

    const int tid = threadIdx.x, lane = tid & 63, w = tid >> 6;
    const int quad = lane >> 4, l16 = lane & 15;
    const int lrow = lane >> 3, lchunk = lane & 7;
    const int sw8 = 8 * (l16 >> 1);

    const int idx = (int)blockIdx.x;
    const int rank = idx >> 6, bh = idx & 63;
    constexpr int jj_tab[16] = {15, 13, 11, 9, 0, 2, 4, 6, 14, 12, 10, 8, 1, 3, 5, 7};
    const int jj = jj_tab[rank];
    const int b = bh >> 4, h = bh & 15;

    const ushort_t* base_k = qk + (size_t)(b * 2048) * 2048 + 1024 + h * 64;
    const ushort_t* base_v = vt + (size_t)bh * 64 * 2048;
    const int vd = w * 4 + (lane >> 4);
    const int vc8 = lane & 15;

    ushort8_t kreg[4], vreg[4];
    auto load_kv = [&](int kt) {
        const ushort_t* gk = base_k + (size_t)(kt * 128) * 2048 + lchunk * 8;
#pragma unroll
        for (int i = 0; i < 4; ++i)
            kreg[i] = *(const ushort8_t*)(gk + (size_t)(w * 32 + i * 8 + lrow) * 2048);
        const ushort_t* gv = base_v + kt * 128;
#pragma unroll
        for (int i = 0; i < 4; ++i)
            vreg[i] = *(const ushort8_t*)(gv + (size_t)(i * 16 + vd) * 2048 + vc8 * 8);
    };
    auto store_kv = [&]() {
#pragma unroll
        for (int i = 0; i < 4; ++i) {
            int row = w * 32 + i * 8 + lrow;
            *(ushort8_t*)&Ks[row * 64 + 8 * (lchunk ^ ((row >> 1) & 7))] = kreg[i];
        }
#pragma unroll
        for (int i = 0; i < 4; ++i)
            *(ushort8_t*)&Vt[(i * 16 + vd) * 136 + vc8 * 8] = vreg[i];
    };

    const int q0 = jj * 128 + w * 32;

    bf16x8 qf[2][2];
    {
        const ushort_t* qb = qk + (size_t)(b * 2048 + q0) * 2048 + h * 64 + quad * 8;
#pragma unroll
        for (int nt = 0; nt < 2; ++nt)
#pragma unroll
            for (int kd = 0; kd < 2; ++kd) {
                ushort8_t raw =
                    *(const ushort8_t*)(qb + (size_t)(nt * 16 + l16) * 2048 + kd * 32);
                uint4_t dw;
#pragma unroll
                for (int jx = 0; jx < 4; ++jx) {
                    float f0 = bf2f(raw[2 * jx]) * ATT_SCALE;
                    float f1 = bf2f(raw[2 * jx + 1]) * ATT_SCALE;
                    dw[jx] = pack_trunc(f0, f1);
                }
                qf[nt][kd] = __builtin_bit_cast(bf16x8, dw);
            }
    }

    floatx4 o[2][4] = {};
    floatx4 lac[2] = {};
    float m_[2] = {-3e38f, -3e38f};

    load_kv(0);
#pragma unroll 1
    for (int kt = 0; kt <= jj; ++kt) {
        __syncthreads();
        store_kv();
        __syncthreads();
        if (kt < jj) load_kv(kt + 1);

        if (kt < jj)
            attn_step<false>(Ks, Vt, qf, o, lac, m_, quad, l16, sw8, 7, 0);
        else
            attn_step<true>(Ks, Vt, qf, o, lac, m_, quad, l16, sw8, 2 * w + 1, w * 32);
    }

    ushort_t* yb = y + (size_t)(b * 2048 + q0) * 1024 + h * 64;
#pragma unroll
    for (int mtq = 0; mtq < 2; ++mtq)
#pragma unroll
        for (int r = 0; r < 4; ++r) {
            float inv = 1.0f / lac[mtq][r];
            int row = mtq * 16 + quad * 4 + r;
#pragma unroll
            for (int ntd = 0; ntd < 4; ++ntd)
                yb[(size_t)row * 1024 + ntd * 16 + l16] = f2bf(o[mtq][ntd][r] * inv);
        }
}

extern "C" void kernel_launch(void* const* d_in, const int* in_sizes, int n_in,
                              void* d_out, int out_size, void* d_ws, size_t ws_size,
                              hipStream_t stream) {
    const float* x = (const float*)d_in[0];
    const float* qkv_w = (const float*)d_in[1];
    const float* c_proj_w = (const float*)d_in[2];
    const float* c_proj_b = (const float*)d_in[3];
    float* out = (float*)d_out;

    // Memory plan (3 kernels, no cvt passes, no aliasing hazards):
    //   ws[0,32M):  qk bf16 [8192 x 2048]       (gemm1 -> attn)
    //   ws[32,48M): vt bf16 [4][16][64][2048]   (gemm1 -> attn)
    //   ws[48,64M): y  bf16 [8192 x 1024]       (attn -> gemm2)
    //   d_out: final fp32 output only (gemm2 full overwrite)
    ushort_t* qk = (ushort_t*)d_ws;
    ushort_t* vt = (ushort_t*)((char*)d_ws + (size_t)33554432);
    ushort_t* y = (ushort_t*)((char*)d_ws + (size_t)50331648);

    // gemm1: qkv = x @ qkv_w^T, fused RoPE + qk/vt split (fp32 inputs, in-stage cvt)
    gemm_f<2><<<dim3(3072 / 128, 8192 / 256), 512, 0, stream>>>(
        nullptr, x, qkv_w, nullptr, qk, vt, 3072);

    attn_kernel<<<dim3(1024), 256, 0, stream>>>(qk, vt, y);

    // gemm2: out = y @ c_proj_w^T + b  (A bf16 from attn, B fp32 in-stage cvt)
    gemm_f<0><<<dim3(1024 / 128, 8192 / 256), 512, 0, stream>>>(
        y, nullptr, c_proj_w, c_proj_b, out, nullptr, 1024);
}

// Round 11
// 254.522 us; speedup vs baseline: 1.1086x; 1.1086x over previous
//
#include <hip/hip_runtime.h>

typedef unsigned short ushort_t;
typedef __bf16 bf16x8 __attribute__((ext_vector_type(8)));
typedef unsigned short ushort8_t __attribute__((ext_vector_type(8)));
typedef unsigned short ushort4_t __attribute__((ext_vector_type(4)));
typedef float floatx4 __attribute__((ext_vector_type(4)));
typedef unsigned int uint4_t __attribute__((ext_vector_type(4)));
typedef unsigned int uint2_t __attribute__((ext_vector_type(2)));

__device__ __forceinline__ ushort_t f2bf(float f) {
    unsigned int u = __float_as_uint(f);
    u += 0x7FFFu + ((u >> 16) & 1u);  // RNE
    return (ushort_t)(u >> 16);
}
__device__ __forceinline__ float bf2f(ushort_t b) {
    return __uint_as_float(((unsigned int)b) << 16);
}
__device__ __forceinline__ bf16x8 ld_frag(const ushort_t* p) {
    ushort8_t u = *(const ushort8_t*)p;
    return __builtin_bit_cast(bf16x8, u);
}
__device__ __forceinline__ unsigned pack_trunc(float lo, float hi) {
    return __builtin_amdgcn_perm(__float_as_uint(hi), __float_as_uint(lo), 0x07060302u);
}
__device__ __forceinline__ floatx4 mfma16(bf16x8 a, bf16x8 b, floatx4 c) {
    return __builtin_amdgcn_mfma_f32_16x16x32_bf16(a, b, c, 0, 0, 0);
}
// async global->LDS, 16B per lane; LDS dest = wave-uniform base + lane*16
__device__ __forceinline__ void async16(const ushort_t* g, ushort_t* l) {
    __builtin_amdgcn_global_load_lds((const __attribute__((address_space(1))) void*)g,
                                     (__attribute__((address_space(3))) void*)l, 16, 0, 0);
}
// dst.high32lanes <-> src.low32lanes (both regs updated)
__device__ __forceinline__ void pl32swap(unsigned& a, unsigned& b) {
    asm volatile("v_permlane32_swap_b32 %0, %1" : "+v"(a), "+v"(b));
}
// dst odd 16-rows <-> src even 16-rows (both regs updated)
__device__ __forceinline__ void pl16swap(unsigned& a, unsigned& b) {
    asm volatile("v_permlane16_swap_b32 %0, %1" : "+v"(a), "+v"(b));
}

// ---------------- fp32 -> bf16 convert, two sources in one launch ----------------
__global__ __launch_bounds__(256) void cvt_dual(const float* __restrict__ s1,
                                                ushort_t* __restrict__ d1, int n1,
                                                const float* __restrict__ s2,
                                                ushort_t* __restrict__ d2, int n2) {
    int idx = blockIdx.x * 256 + threadIdx.x;
    const float* src;
    ushort_t* dst;
    if (idx < n1) {
        src = s1; dst = d1;
    } else {
        idx -= n1;
        if (idx >= n2) return;
        src = s2; dst = d2;
    }
    const float4* s = (const float4*)src + (size_t)idx * 2;
    float4 a = s[0], b = s[1];
    ushort8_t v;
    v[0] = f2bf(a.x); v[1] = f2bf(a.y); v[2] = f2bf(a.z); v[3] = f2bf(a.w);
    v[4] = f2bf(b.x); v[5] = f2bf(b.y); v[6] = f2bf(b.z); v[7] = f2bf(b.w);
    *(ushort8_t*)(dst + (size_t)idx * 8) = v;
}

// ---------------- gemm_big: round-8 kernel (for gemm1: many-round grid) ----------------
// 256x128 tile, 512 threads (8 waves 4Mx2N), BK=64, 3 LDS buffers (144KB),
// 2-tile-deep prefetch, counted vmcnt(6) fused with s_barrier, T2 swizzle.
// Measured: 74.6us, MfmaUtil 26.8, bank conflicts 0 (round 8).
template <int MODE>
__global__ __launch_bounds__(512, 2) void gemm_big(const ushort_t* __restrict__ A,
                                                   const ushort_t* __restrict__ B,
                                                   const float* __restrict__ bias,
                                                   void* __restrict__ Cout,
                                                   ushort_t* __restrict__ vt,
                                                   int M, int N) {
    constexpr int K = 1024;
    __shared__ __attribute__((aligned(16))) ushort_t As[3][256 * 64];  // 3 x 32KB
    __shared__ __attribute__((aligned(16))) ushort_t Bs[3][128 * 64];  // 3 x 16KB
    const int tid = threadIdx.x;
    const int lane = tid & 63, w = tid >> 6;
    const int quad = lane >> 4, l16 = lane & 15;
    const int wm = w >> 1, wn = w & 1;  // 4M x 2N wave grid
    const int m0 = blockIdx.y * 256, n0 = blockIdx.x * 128;

    const int lr = lane >> 3, lc = lane & 7;
    const int swc = lc ^ lr;        // pre-swizzled source col-chunk (T2)
    const int rsw = (l16 & 7) * 8;  // read-side XOR

    const ushort_t* ga[4];
    const ushort_t* gb[2];
#pragma unroll
    for (int i = 0; i < 4; ++i)
        ga[i] = A + (size_t)(m0 + i * 64 + w * 8 + lr) * K + swc * 8;
#pragma unroll
    for (int i = 0; i < 2; ++i)
        gb[i] = B + (size_t)(n0 + i * 64 + w * 8 + lr) * K + swc * 8;

    floatx4 acc[4][4] = {};

    // prologue: tile 0 -> buf0, tile 1 -> buf1 (6 loads each); wait tile 0 only.
#pragma unroll
    for (int i = 0; i < 4; ++i) async16(ga[i], &As[0][i * 4096 + w * 512]);
#pragma unroll
    for (int i = 0; i < 2; ++i) async16(gb[i], &Bs[0][i * 4096 + w * 512]);
#pragma unroll
    for (int i = 0; i < 4; ++i) async16(ga[i] + 64, &As[1][i * 4096 + w * 512]);
#pragma unroll
    for (int i = 0; i < 2; ++i) async16(gb[i] + 64, &Bs[1][i * 4096 + w * 512]);
    asm volatile("s_waitcnt vmcnt(6)\ns_barrier" ::: "memory");

#pragma unroll
    for (int t = 0; t < 16; ++t) {
        const int cb = t % 3;
        const int nb = (t + 2) % 3;

        // ---- phase A: B frags (all) + A frags mt=0,1 ; stage A[0..2] of t+2
        bf16x8 bfr[4][2], afA[2][2];
#pragma unroll
        for (int nt = 0; nt < 4; ++nt)
#pragma unroll
            for (int ks = 0; ks < 2; ++ks)
                bfr[nt][ks] = ld_frag(&Bs[cb][(wn * 64 + nt * 16 + l16) * 64 +
                                              ((ks * 32 + quad * 8) ^ rsw)]);
#pragma unroll
        for (int mt = 0; mt < 2; ++mt)
#pragma unroll
            for (int ks = 0; ks < 2; ++ks)
                afA[mt][ks] = ld_frag(&As[cb][(wm * 64 + mt * 16 + l16) * 64 +
                                              ((ks * 32 + quad * 8) ^ rsw)]);
        if (t < 14) {
            async16(ga[0] + (t + 2) * 64, &As[nb][0 * 4096 + w * 512]);
            async16(ga[1] + (t + 2) * 64, &As[nb][1 * 4096 + w * 512]);
            async16(ga[2] + (t + 2) * 64, &As[nb][2 * 4096 + w * 512]);
        }
        __builtin_amdgcn_s_barrier();
        __builtin_amdgcn_s_setprio(1);
#pragma unroll
        for (int mt = 0; mt < 2; ++mt)
#pragma unroll
            for (int nt = 0; nt < 4; ++nt) {
                acc[mt][nt] = mfma16(afA[mt][0], bfr[nt][0], acc[mt][nt]);
                acc[mt][nt] = mfma16(afA[mt][1], bfr[nt][1], acc[mt][nt]);
            }
        __builtin_amdgcn_s_setprio(0);
        __builtin_amdgcn_s_barrier();

        // ---- phase B: A frags mt=2,3 ; stage A[3] + B[0,1] of t+2
        bf16x8 afB[2][2];
#pragma unroll
        for (int mt = 0; mt < 2; ++mt)
#pragma unroll
            for (int ks = 0; ks < 2; ++ks)
                afB[mt][ks] = ld_frag(&As[cb][(wm * 64 + (mt + 2) * 16 + l16) * 64 +
                                              ((ks * 32 + quad * 8) ^ rsw)]);
        if (t < 14) {
            async16(ga[3] + (t + 2) * 64, &As[nb][3 * 4096 + w * 512]);
            async16(gb[0] + (t + 2) * 64, &Bs[nb][0 * 4096 + w * 512]);
            async16(gb[1] + (t + 2) * 64, &Bs[nb][1 * 4096 + w * 512]);
        }
        __builtin_amdgcn_s_barrier();
        __builtin_amdgcn_s_setprio(1);
#pragma unroll
        for (int mt = 0; mt < 2; ++mt)
#pragma unroll
            for (int nt = 0; nt < 4; ++nt) {
                acc[mt + 2][nt] = mfma16(afB[mt][0], bfr[nt][0], acc[mt + 2][nt]);
                acc[mt + 2][nt] = mfma16(afB[mt][1], bfr[nt][1], acc[mt + 2][nt]);
            }
        __builtin_amdgcn_s_setprio(0);

        // ---- end of step: counted vmcnt FUSED with barrier (T4)
        if (t < 14)
            asm volatile("s_waitcnt vmcnt(6)\ns_barrier" ::: "memory");
        else if (t == 14)
            asm volatile("s_waitcnt vmcnt(0)\ns_barrier" ::: "memory");
    }

    if constexpr (MODE == 2) {
        // fused RoPE on q/k heads (wave spans exactly one 64-wide head)
        if (n0 + wn * 64 < 2048) {
            float afreq = exp2f((float)l16 * (-10.0f / 15.0f));
#pragma unroll
            for (int mt = 0; mt < 4; ++mt) {
                int rowb = m0 + wm * 64 + mt * 16 + quad * 4;
#pragma unroll
                for (int r = 0; r < 4; ++r) {
                    int t = (rowb + r) & 2047;
                    float th = (float)t * afreq;
                    float sn, cs;
                    __sincosf(th, &sn, &cs);
                    float q1 = acc[mt][0][r], q2 = acc[mt][2][r];
                    acc[mt][0][r] = q1 * cs + q2 * sn;
                    acc[mt][2][r] = -q1 * sn + q2 * cs;
                }
            }
        }
    }

#pragma unroll
    for (int mt = 0; mt < 4; ++mt) {
        int row = m0 + wm * 64 + mt * 16 + quad * 4;
#pragma unroll
        for (int nt = 0; nt < 4; ++nt) {
            int nglob = n0 + wn * 64 + nt * 16 + l16;
            if constexpr (MODE == 0) {
                float bv = bias ? bias[nglob] : 0.0f;
#pragma unroll
                for (int r = 0; r < 4; ++r)
                    ((float*)Cout)[(size_t)(row + r) * N + nglob] = acc[mt][nt][r] + bv;
            } else {
                if (nglob < 2048) {
#pragma unroll
                    for (int r = 0; r < 4; ++r)
                        ((ushort_t*)Cout)[(size_t)(row + r) * 2048 + nglob] =
                            f2bf(acc[mt][nt][r]);
                } else {
                    int d = nglob & 63, hh = (nglob >> 6) & 15;
                    int bb = row >> 11, t = row & 2047;
                    ushort4_t pk;
                    pk.x = f2bf(acc[mt][nt][0]);
                    pk.y = f2bf(acc[mt][nt][1]);
                    pk.z = f2bf(acc[mt][nt][2]);
                    pk.w = f2bf(acc[mt][nt][3]);
                    *(ushort4_t*)&vt[(((size_t)bb * 16 + hh) * 64 + d) * 2048 + t] = pk;
                }
            }
        }
    }
}

// ---------------- gemm_small: round-6 kernel (for gemm2: single-pass grid) ----------------
// 128x128 tile, 256 threads, BK=64, 2 LDS buffers (64KB -> 2 blocks/CU),
// T2 swizzle; grid 512 blocks = 2 rounds at 2/CU -> inter-block latency hiding
// that the 1-block/CU big kernel lacks on a 1-round grid (measured: round-8
// gemm2 at 1 round/1 per CU = 74.8us; this shape ran ~30us in rounds 3-6).
template <int MODE>
__global__ __launch_bounds__(256) void gemm_small(const ushort_t* __restrict__ A,
                                                  const ushort_t* __restrict__ B,
                                                  const float* __restrict__ bias,
                                                  void* __restrict__ Cout,
                                                  ushort_t* __restrict__ vt,
                                                  int M, int N) {
    constexpr int K = 1024;
    __shared__ __attribute__((aligned(16))) ushort_t As[2][128 * 64];
    __shared__ __attribute__((aligned(16))) ushort_t Bs[2][128 * 64];
    const int tid = threadIdx.x;
    const int lane = tid & 63, wave = tid >> 6;
    const int quad = lane >> 4, l16 = lane & 15;
    const int wm = wave & 1, wn = wave >> 1;
    const int m0 = blockIdx.y * 128, n0 = blockIdx.x * 128;

    const int lr = lane >> 3, lc = lane & 7;
    const int swc = lc ^ lr;  // pre-swizzled source col-chunk
    const ushort_t* ga = A + (size_t)(m0 + wave * 32 + lr) * K + swc * 8;
    const ushort_t* gb = B + (size_t)(n0 + wave * 32 + lr) * K + swc * 8;
    const int woff = wave * 2048;

    floatx4 acc[4][4] = {};

    const int rsw = (l16 & 7) * 8;  // read-side XOR (row&7)*8

    auto stage = [&](int kt, int buf) {
#pragma unroll
        for (int i = 0; i < 4; ++i) {
            async16(ga + (size_t)kt * 64 + (size_t)i * 8 * K, &As[buf][woff + i * 512]);
            async16(gb + (size_t)kt * 64 + (size_t)i * 8 * K, &Bs[buf][woff + i * 512]);
        }
    };

    stage(0, 0);
    asm volatile("s_waitcnt vmcnt(0)" ::: "memory");
    __builtin_amdgcn_s_barrier();

#pragma unroll
    for (int t = 0; t < 16; ++t) {
        const int cb = t & 1;
        if (t < 15) stage(t + 1, cb ^ 1);

        bf16x8 af[4][2], bfr[4][2];
#pragma unroll
        for (int mt = 0; mt < 4; ++mt)
#pragma unroll
            for (int ks = 0; ks < 2; ++ks)
                af[mt][ks] = ld_frag(
                    &As[cb][(wm * 64 + mt * 16 + l16) * 64 + ((ks * 32 + quad * 8) ^ rsw)]);
#pragma unroll
        for (int nt = 0; nt < 4; ++nt)
#pragma unroll
            for (int ks = 0; ks < 2; ++ks)
                bfr[nt][ks] = ld_frag(
                    &Bs[cb][(wn * 64 + nt * 16 + l16) * 64 + ((ks * 32 + quad * 8) ^ rsw)]);
#pragma unroll
        for (int mt = 0; mt < 4; ++mt)
#pragma unroll
            for (int nt = 0; nt < 4; ++nt) {
                acc[mt][nt] = mfma16(af[mt][0], bfr[nt][0], acc[mt][nt]);
                acc[mt][nt] = mfma16(af[mt][1], bfr[nt][1], acc[mt][nt]);
            }

        asm volatile("s_waitcnt vmcnt(0)" ::: "memory");
        __builtin_amdgcn_s_barrier();
    }

#pragma unroll
    for (int mt = 0; mt < 4; ++mt) {
        int row = m0 + wm * 64 + mt * 16 + quad * 4;
#pragma unroll
        for (int nt = 0; nt < 4; ++nt) {
            int nglob = n0 + wn * 64 + nt * 16 + l16;
            float bv = bias ? bias[nglob] : 0.0f;
#pragma unroll
            for (int r = 0; r < 4; ++r)
                ((float*)Cout)[(size_t)(row + r) * N + nglob] = acc[mt][nt][r] + bv;
        }
    }
}

// ---------------- Flash attention (round 7/8 permlane version) ----------------
#define ATT_SCALE 0.18033688011112042f /* 0.125 * log2(e) */

template <bool DIAG>
__device__ __forceinline__ void attn_step(
    const ushort_t* __restrict__ Ks, const ushort_t* __restrict__ Vt,
    const bf16x8 (&qf)[2][2], floatx4 (&o)[2][4], floatx4 (&lac)[2], float (&m_)[2],
    int quad, int l16, int sw8, int mhi, int qrel) {
    ushort8_t ou;
#pragma unroll
    for (int j = 0; j < 8; ++j) ou[j] = 0x3F80;
    const bf16x8 vONE = __builtin_bit_cast(bf16x8, ou);

    // ---- QK^T from LDS-staged K ----
    floatx4 s[8][2];
    __builtin_amdgcn_s_setprio(1);
#pragma unroll
    for (int mt = 0; mt < 8; ++mt) {
        if (DIAG && mt > mhi) continue;
        const ushort_t* kr = &Ks[(mt * 16 + l16) * 64];
        bf16x8 k0 = ld_frag(kr + ((quad * 8) ^ sw8));
        bf16x8 k1 = ld_frag(kr + ((32 + quad * 8) ^ sw8));
#pragma unroll
        for (int nt = 0; nt < 2; ++nt) {
            floatx4 z = {};
            z = mfma16(k0, qf[nt][0], z);
            s[mt][nt] = mfma16(k1, qf[nt][1], z);
        }
    }
    __builtin_amdgcn_s_setprio(0);

    if (DIAG) {
#pragma unroll
        for (int mt = 0; mt < 8; ++mt) {
            if (mt > mhi) continue;
#pragma unroll
            for (int nt = 0; nt < 2; ++nt)
#pragma unroll
                for (int r = 0; r < 4; ++r)
                    if (mt * 16 + quad * 4 + r > qrel + nt * 16 + l16)
                        s[mt][nt][r] = -3e38f;
        }
    }

    // ---- online softmax with defer-max (T13) ----
    float mx[2];
#pragma unroll
    for (int nt = 0; nt < 2; ++nt) {
        float m0 = -3e38f;
#pragma unroll
        for (int mt = 0; mt < 8; ++mt) {
            if (DIAG && mt > mhi) continue;
            m0 = fmaxf(m0, fmaxf(fmaxf(s[mt][nt][0], s[mt][nt][1]),
                                 fmaxf(s[mt][nt][2], s[mt][nt][3])));
        }
        m0 = fmaxf(m0, __shfl_xor(m0, 16));
        m0 = fmaxf(m0, __shfl_xor(m0, 32));
        mx[nt] = m0;
    }
    bool resc = !__all((mx[0] - m_[0] <= 8.0f) && (mx[1] - m_[1] <= 8.0f));
    if (resc) {
        float alpha_l[2];
#pragma unroll
        for (int nt = 0; nt < 2; ++nt) {
            float mnew = fmaxf(m_[nt], mx[nt]);
            alpha_l[nt] = __builtin_amdgcn_exp2f(m_[nt] - mnew);
            m_[nt] = mnew;
        }
#pragma unroll
        for (int mtq = 0; mtq < 2; ++mtq)
#pragma unroll
            for (int r = 0; r < 4; ++r) {
                float ao = __shfl(alpha_l[mtq], quad * 4 + r);
                lac[mtq][r] *= ao;
#pragma unroll
                for (int ntd = 0; ntd < 4; ++ntd) o[mtq][ntd][r] *= ao;
            }
    }
#pragma unroll
    for (int nt = 0; nt < 2; ++nt)
#pragma unroll
        for (int mt = 0; mt < 8; ++mt) {
            if (DIAG && mt > mhi) continue;
#pragma unroll
            for (int r = 0; r < 4; ++r)
                s[mt][nt][r] = __builtin_amdgcn_exp2f(s[mt][nt][r] - m_[nt]);
        }

    // ---- in-register P transpose (verified round 2) ----
    uint2_t pk[2][8];
#pragma unroll
    for (int nt = 0; nt < 2; ++nt)
#pragma unroll
        for (int mt = 0; mt < 8; ++mt) {
            if (DIAG && mt > mhi) continue;
            pk[nt][mt].x = pack_trunc(s[mt][nt][0], s[mt][nt][1]);
            pk[nt][mt].y = pack_trunc(s[mt][nt][2], s[mt][nt][3]);
        }

    __builtin_amdgcn_s_setprio(1);
#pragma unroll
    for (int kc = 0; kc < 4; ++kc) {
        if (DIAG && kc > (mhi >> 1)) continue;
        bf16x8 ap[2];
#pragma unroll
        for (int nt = 0; nt < 2; ++nt) {
            unsigned a0 = pk[nt][2 * kc].x, a1 = pk[nt][2 * kc].y;
            unsigned b0 = pk[nt][2 * kc + 1].x, b1 = pk[nt][2 * kc + 1].y;
            pl32swap(a0, b0);
            pl16swap(a0, b0);
            pl32swap(a1, b1);
            pl16swap(a1, b1);
            uint4_t ud;
            ud[0] = a0; ud[1] = a1; ud[2] = b0; ud[3] = b1;
            ap[nt] = __builtin_bit_cast(bf16x8, ud);
        }
        lac[0] = mfma16(ap[0], vONE, lac[0]);
        lac[1] = mfma16(ap[1], vONE, lac[1]);
#pragma unroll
        for (int ntd = 0; ntd < 4; ++ntd) {
            bf16x8 bv = ld_frag(&Vt[(ntd * 16 + l16) * 136 + kc * 32 + quad * 8]);
            o[0][ntd] = mfma16(ap[0], bv, o[0][ntd]);
            o[1][ntd] = mfma16(ap[1], bv, o[1][ntd]);
        }
    }
    __builtin_amdgcn_s_setprio(0);
}

__global__ __launch_bounds__(256, 2) void attn_kernel(const ushort_t* __restrict__ qk,
                                                      const ushort_t* __restrict__ vt,
                                                      ushort_t* __restrict__ y) {
    __shared__ __attribute__((aligned(16))) ushort_t Ks[128 * 64];   // 16 KB
    __shared__ __attribute__((aligned(16))) ushort_t Vt[64 * 136];   // 17 KB

    const int tid = threadIdx.x, lane = tid & 63, w = tid >> 6;
    const int quad = lane >> 4, l16 = lane & 15;
    const int lrow = lane >> 3, lchunk = lane & 7;
    const int sw8 = 8 * (l16 >> 1);

    const int idx = (int)blockIdx.x;
    const int rank = idx >> 6, bh = idx & 63;
    constexpr int jj_tab[16] = {15, 13, 11, 9, 0, 2, 4, 6, 14, 12, 10, 8, 1, 3, 5, 7};
    const int jj = jj_tab[rank];
    const int b = bh >> 4, h = bh & 15;

    const ushort_t* base_k = qk + (size_t)(b * 2048) * 2048 + 1024 + h * 64;
    const ushort_t* base_v = vt + (size_t)bh * 64 * 2048;
    const int vd = w * 4 + (lane >> 4);
    const int vc8 = lane & 15;

    ushort8_t kreg[4], vreg[4];
    auto load_kv = [&](int kt) {
        const ushort_t* gk = base_k + (size_t)(kt * 128) * 2048 + lchunk * 8;
#pragma unroll
        for (int i = 0; i < 4; ++i)
            kreg[i] = *(const ushort8_t*)(gk + (size_t)(w * 32 + i * 8 + lrow) * 2048);
        const ushort_t* gv = base_v + kt * 128;
#pragma unroll
        for (int i = 0; i < 4; ++i)
            vreg[i] = *(const ushort8_t*)(gv + (size_t)(i * 16 + vd) * 2048 + vc8 * 8);
    };
    auto store_kv = [&]() {
#pragma unroll
        for (int i = 0; i < 4; ++i) {
            int row = w * 32 + i * 8 + lrow;
            *(ushort8_t*)&Ks[row * 64 + 8 * (lchunk ^ ((row >> 1) & 7))] = kreg[i];
        }
#pragma unroll
        for (int i = 0; i < 4; ++i)
            *(ushort8_t*)&Vt[(i * 16 + vd) * 136 + vc8 * 8] = vreg[i];
    };

    const int q0 = jj * 128 + w * 32;

    bf16x8 qf[2][2];
    {
        const ushort_t* qb = qk + (size_t)(b * 2048 + q0) * 2048 + h * 64 + quad * 8;
#pragma unroll
        for (int nt = 0; nt < 2; ++nt)
#pragma unroll
            for (int kd = 0; kd < 2; ++kd) {
                ushort8_t raw =
                    *(const ushort8_t*)(qb + (size_t)(nt * 16 + l16) * 2048 + kd * 32);
                uint4_t dw;
#pragma unroll
                for (int jx = 0; jx < 4; ++jx) {
                    float f0 = bf2f(raw[2 * jx]) * ATT_SCALE;
                    float f1 = bf2f(raw[2 * jx + 1]) * ATT_SCALE;
                    dw[jx] = pack_trunc(f0, f1);
                }
                qf[nt][kd] = __builtin_bit_cast(bf16x8, dw);
            }
    }

    floatx4 o[2][4] = {};
    floatx4 lac[2] = {};
    float m_[2] = {-3e38f, -3e38f};

    load_kv(0);
#pragma unroll 1
    for (int kt = 0; kt <= jj; ++kt) {
        __syncthreads();
        store_kv();
        __syncthreads();
        if (kt < jj) load_kv(kt + 1);

        if (kt < jj)
            attn_step<false>(Ks, Vt, qf, o, lac, m_, quad, l16, sw8, 7, 0);
        else
            attn_step<true>(Ks, Vt, qf, o, lac, m_, quad, l16, sw8, 2 * w + 1, w * 32);
    }

    ushort_t* yb = y + (size_t)(b * 2048 + q0) * 1024 + h * 64;
#pragma unroll
    for (int mtq = 0; mtq < 2; ++mtq)
#pragma unroll
        for (int r = 0; r < 4; ++r) {
            float inv = 1.0f / lac[mtq][r];
            int row = mtq * 16 + quad * 4 + r;
#pragma unroll
            for (int ntd = 0; ntd < 4; ++ntd)
                yb[(size_t)row * 1024 + ntd * 16 + l16] = f2bf(o[mtq][ntd][r] * inv);
        }
}

extern "C" void kernel_launch(void* const* d_in, const int* in_sizes, int n_in,
                              void* d_out, int out_size, void* d_ws, size_t ws_size,
                              hipStream_t stream) {
    const float* x = (const float*)d_in[0];
    const float* qkv_w = (const float*)d_in[1];
    const float* c_proj_w = (const float*)d_in[2];
    const float* c_proj_b = (const float*)d_in[3];
    float* out = (float*)d_out;

    const int M = 8192;  // B*T

    // Memory plan (time-multiplexed):
    //   d_out (32MB fp32): xb bf16 [8192x1024] during gemm1 (dead after);
    //                      final fp32 output written by gemm2 (full overwrite).
    //   ws[0,32M):  qk bf16 [8192 x 2048]       (gemm1 -> attn)
    //   ws[32,48M): vt bf16 [4][16][64][2048]   (gemm1 -> attn); first 2MB reused
    //               as wpb (c_proj_w bf16) after attn
    //   ws[48,64M): wb bf16 [3072x1024] (qkv_w) during gemm1 (dead after);
    //               y bf16 [8192x1024] written by attn (overwrites wb)
    ushort_t* qk = (ushort_t*)d_ws;
    ushort_t* vt = (ushort_t*)((char*)d_ws + (size_t)33554432);
    ushort_t* wpb = vt;
    ushort_t* wb = (ushort_t*)((char*)d_ws + (size_t)50331648);
    ushort_t* y = wb;
    ushort_t* xb = (ushort_t*)d_out;

    cvt_dual<<<dim3(5632), 256, 0, stream>>>(x, xb, M * 1024 / 8,
                                             qkv_w, wb, 3072 * 1024 / 8);

    gemm_big<2><<<dim3(3072 / 128, 8192 / 256), 512, 0, stream>>>(
        xb, wb, nullptr, qk, vt, M, 3072);

    attn_kernel<<<dim3(1024), 256, 0, stream>>>(qk, vt, y);

    cvt_dual<<<dim3(512), 256, 0, stream>>>(c_proj_w, wpb, 1024 * 1024 / 8,
                                            nullptr, nullptr, 0);

    gemm_small<0><<<dim3(1024 / 128, 8192 / 128), 256, 0, stream>>>(
        y, wpb, c_proj_b, out, nullptr, M, 1024);
}